// Round 1
// baseline (1582.162 us; speedup 1.0000x reference)
//
#include <hip/hip_runtime.h>

#define N_NODES 100000
#define IN_F 256
#define OUT_F 128

typedef __attribute__((ext_vector_type(8))) short v8s;
typedef __attribute__((ext_vector_type(4))) float v4f;

// RNE fp32 -> bf16 (bit trick; inputs are finite)
__device__ __forceinline__ unsigned short f2bf(float f) {
    unsigned int u = __float_as_uint(f);
    u += 0x7fffu + ((u >> 16) & 1u);
    return (unsigned short)(u >> 16);
}

// weight [K=256][F=128] fp32 -> bt bf16 [F=128][K=256]  (transpose + convert, once)
__global__ void wt_kernel(const float* __restrict__ w, unsigned short* __restrict__ bt) {
    int idx = blockIdx.x * 256 + threadIdx.x;   // 0..32767
    int k = idx >> 7;
    int n = idx & 127;
    bt[n * IN_F + k] = f2bf(w[idx]);
}

// Fused dropout + cast + GEMM: support[N][128] = dropout(input) @ weight
// 128 rows per block, 4 waves each computing a 64x64 quadrant (4x4 tiles of 16x16x32 MFMA)
__global__ __launch_bounds__(256) void gemm_kernel(
    const float* __restrict__ input, const float* __restrict__ drop_u,
    const unsigned short* __restrict__ bt, float* __restrict__ support) {
    // stride 72 bf16 (=144B): keeps ds_read_b128 16B-aligned, 2-way bank aliasing (free)
    __shared__ unsigned short As[128 * 72];
    __shared__ unsigned short Bs[128 * 72];

    const int tid  = threadIdx.x;
    const int lane = tid & 63;
    const int wv   = tid >> 6;
    const int wr   = wv >> 1, wc = wv & 1;
    const long long base = (long long)blockIdx.x * 128;

    v4f acc[4][4] = {};

    for (int k0 = 0; k0 < IN_F; k0 += 64) {
        if (k0) __syncthreads();
        // ---- stage A: 128 rows x 64 k, fused dropout + bf16 convert ----
        {
            const int r0 = tid >> 4;            // 0..15
            const int cc = (tid & 15) * 4;      // 0..60
            #pragma unroll
            for (int p = 0; p < 8; ++p) {
                int row = p * 16 + r0;
                long long g = base + row;
                float4 xi = {0.f, 0.f, 0.f, 0.f};
                float4 du = {0.f, 0.f, 0.f, 0.f};
                if (g < N_NODES) {
                    xi = *(const float4*)(input + g * IN_F + k0 + cc);
                    du = *(const float4*)(drop_u + g * IN_F + k0 + cc);
                }
                ushort4 pk;
                pk.x = f2bf(du.x > 0.2f ? xi.x * 1.25f : 0.0f);
                pk.y = f2bf(du.y > 0.2f ? xi.y * 1.25f : 0.0f);
                pk.z = f2bf(du.z > 0.2f ? xi.z * 1.25f : 0.0f);
                pk.w = f2bf(du.w > 0.2f ? xi.w * 1.25f : 0.0f);
                *(ushort4*)&As[row * 72 + cc] = pk;
            }
        }
        // ---- stage B^T: 128 cols x 64 k from precomputed bt ----
        {
            const int n  = tid >> 1;            // 0..127
            const int kh = (tid & 1) * 32;
            const unsigned short* src = bt + n * IN_F + k0 + kh;
            unsigned short* dst = &Bs[n * 72 + kh];
            #pragma unroll
            for (int i = 0; i < 4; ++i)
                *(v8s*)(dst + i * 8) = *(const v8s*)(src + i * 8);
        }
        __syncthreads();
        // ---- MFMA: 2 k-steps of 32 over this 64-wide chunk ----
        #pragma unroll
        for (int ks = 0; ks < 2; ++ks) {
            const int kb = ks * 32 + (lane >> 4) * 8;
            v8s af[4], bf[4];
            #pragma unroll
            for (int t = 0; t < 4; ++t)
                af[t] = *(const v8s*)&As[(wr * 64 + t * 16 + (lane & 15)) * 72 + kb];
            #pragma unroll
            for (int t = 0; t < 4; ++t)
                bf[t] = *(const v8s*)&Bs[(wc * 64 + t * 16 + (lane & 15)) * 72 + kb];
            #pragma unroll
            for (int tm = 0; tm < 4; ++tm)
                #pragma unroll
                for (int tn = 0; tn < 4; ++tn)
                    acc[tm][tn] = __builtin_amdgcn_mfma_f32_16x16x32_bf16(
                        af[tm], bf[tn], acc[tm][tn], 0, 0, 0);
        }
    }
    // ---- epilogue: C/D layout col=lane&15, row=(lane>>4)*4+reg (m89/m91) ----
    const int rq = lane >> 4;
    const int cl = lane & 15;
    #pragma unroll
    for (int tm = 0; tm < 4; ++tm) {
        #pragma unroll
        for (int r = 0; r < 4; ++r) {
            long long g = base + wr * 64 + tm * 16 + rq * 4 + r;
            if (g < N_NODES) {
                float* o = support + g * OUT_F + wc * 64 + cl;
                #pragma unroll
                for (int tn = 0; tn < 4; ++tn)
                    o[tn * 16] = acc[tm][tn][r];
            }
        }
    }
}

// SpMM scatter: one wave per edge, lane handles 2 columns via fp32 HW atomics
__global__ __launch_bounds__(256) void spmm_kernel(
    const int* __restrict__ adj_row, const int* __restrict__ adj_col,
    const float* __restrict__ adj_val, const float* __restrict__ support,
    float* __restrict__ out, int E) {
    const int lane = threadIdx.x & 63;
    const int wid  = (blockIdx.x * blockDim.x + threadIdx.x) >> 6;
    const int nw   = (gridDim.x * blockDim.x) >> 6;
    for (int e = wid; e < E; e += nw) {
        int r = adj_row[e];
        int c = adj_col[e];
        float v = adj_val[e];
        float2 s = *(const float2*)(support + (long long)c * OUT_F + lane * 2);
        float* o = out + (long long)r * OUT_F + lane * 2;
        unsafeAtomicAdd(o,     v * s.x);
        unsafeAtomicAdd(o + 1, v * s.y);
    }
}

extern "C" void kernel_launch(void* const* d_in, const int* in_sizes, int n_in,
                              void* d_out, int out_size, void* d_ws, size_t ws_size,
                              hipStream_t stream) {
    const float* input   = (const float*)d_in[0];
    const float* weight  = (const float*)d_in[1];
    const int*   adj_row = (const int*)d_in[2];
    const int*   adj_col = (const int*)d_in[3];
    const float* adj_val = (const float*)d_in[4];
    const float* drop_u  = (const float*)d_in[5];
    float* out = (float*)d_out;
    const int E = in_sizes[2];

    // ws layout: [0, 64KB): bt bf16 [128][256]; [64KB, +51.2MB): support fp32 [N][128]
    unsigned short* bt = (unsigned short*)d_ws;
    float* support = (float*)((char*)d_ws + 65536);

    hipMemsetAsync(d_out, 0, (size_t)out_size * sizeof(float), stream);
    wt_kernel<<<128, 256, 0, stream>>>(weight, bt);
    gemm_kernel<<<(N_NODES + 127) / 128, 256, 0, stream>>>(input, drop_u, bt, support);
    spmm_kernel<<<2048, 256, 0, stream>>>(adj_row, adj_col, adj_val, support, out, E);
}

// Round 2
// 583.309 us; speedup vs baseline: 2.7124x; 2.7124x over previous
//
#include <hip/hip_runtime.h>

#define N_NODES 100000
#define IN_F 256
#define OUT_F 128
#define NB_SCAN ((N_NODES + 255) / 256)   // 391 scan blocks

typedef __attribute__((ext_vector_type(8))) short v8s;
typedef __attribute__((ext_vector_type(4))) float v4f;

// RNE fp32 -> bf16 (bit trick; inputs are finite)
__device__ __forceinline__ unsigned short f2bf(float f) {
    unsigned int u = __float_as_uint(f);
    u += 0x7fffu + ((u >> 16) & 1u);
    return (unsigned short)(u >> 16);
}

// weight [K=256][F=128] fp32 -> bt bf16 [F=128][K=256]  (transpose + convert, once)
__global__ void wt_kernel(const float* __restrict__ w, unsigned short* __restrict__ bt) {
    int idx = blockIdx.x * 256 + threadIdx.x;   // 0..32767
    int k = idx >> 7;
    int n = idx & 127;
    bt[n * IN_F + k] = f2bf(w[idx]);
}

// Fused dropout + cast + GEMM: support[N][128] = dropout(input) @ weight
__global__ __launch_bounds__(256) void gemm_kernel(
    const float* __restrict__ input, const float* __restrict__ drop_u,
    const unsigned short* __restrict__ bt, float* __restrict__ support) {
    __shared__ unsigned short As[128 * 72];
    __shared__ unsigned short Bs[128 * 72];

    const int tid  = threadIdx.x;
    const int lane = tid & 63;
    const int wv   = tid >> 6;
    const int wr   = wv >> 1, wc = wv & 1;
    const long long base = (long long)blockIdx.x * 128;

    v4f acc[4][4] = {};

    for (int k0 = 0; k0 < IN_F; k0 += 64) {
        if (k0) __syncthreads();
        {
            const int r0 = tid >> 4;            // 0..15
            const int cc = (tid & 15) * 4;      // 0..60
            #pragma unroll
            for (int p = 0; p < 8; ++p) {
                int row = p * 16 + r0;
                long long g = base + row;
                float4 xi = {0.f, 0.f, 0.f, 0.f};
                float4 du = {0.f, 0.f, 0.f, 0.f};
                if (g < N_NODES) {
                    xi = *(const float4*)(input + g * IN_F + k0 + cc);
                    du = *(const float4*)(drop_u + g * IN_F + k0 + cc);
                }
                ushort4 pk;
                pk.x = f2bf(du.x > 0.2f ? xi.x * 1.25f : 0.0f);
                pk.y = f2bf(du.y > 0.2f ? xi.y * 1.25f : 0.0f);
                pk.z = f2bf(du.z > 0.2f ? xi.z * 1.25f : 0.0f);
                pk.w = f2bf(du.w > 0.2f ? xi.w * 1.25f : 0.0f);
                *(ushort4*)&As[row * 72 + cc] = pk;
            }
        }
        {
            const int n  = tid >> 1;            // 0..127
            const int kh = (tid & 1) * 32;
            const unsigned short* src = bt + n * IN_F + k0 + kh;
            unsigned short* dst = &Bs[n * 72 + kh];
            #pragma unroll
            for (int i = 0; i < 4; ++i)
                *(v8s*)(dst + i * 8) = *(const v8s*)(src + i * 8);
        }
        __syncthreads();
        #pragma unroll
        for (int ks = 0; ks < 2; ++ks) {
            const int kb = ks * 32 + (lane >> 4) * 8;
            v8s af[4], bf[4];
            #pragma unroll
            for (int t = 0; t < 4; ++t)
                af[t] = *(const v8s*)&As[(wr * 64 + t * 16 + (lane & 15)) * 72 + kb];
            #pragma unroll
            for (int t = 0; t < 4; ++t)
                bf[t] = *(const v8s*)&Bs[(wc * 64 + t * 16 + (lane & 15)) * 72 + kb];
            #pragma unroll
            for (int tm = 0; tm < 4; ++tm)
                #pragma unroll
                for (int tn = 0; tn < 4; ++tn)
                    acc[tm][tn] = __builtin_amdgcn_mfma_f32_16x16x32_bf16(
                        af[tm], bf[tn], acc[tm][tn], 0, 0, 0);
        }
    }
    const int rq = lane >> 4;
    const int cl = lane & 15;
    #pragma unroll
    for (int tm = 0; tm < 4; ++tm) {
        #pragma unroll
        for (int r = 0; r < 4; ++r) {
            long long g = base + wr * 64 + tm * 16 + rq * 4 + r;
            if (g < N_NODES) {
                float* o = support + g * OUT_F + wc * 64 + cl;
                #pragma unroll
                for (int tn = 0; tn < 4; ++tn)
                    o[tn * 16] = acc[tm][tn][r];
            }
        }
    }
}

// ---- counting-sort build of row-grouped edge list ----

__global__ __launch_bounds__(256) void hist_kernel(
    const int* __restrict__ row, int* __restrict__ cnt, int E) {
    int i = blockIdx.x * 256 + threadIdx.x;
    int n = gridDim.x * 256;
    for (; i < E; i += n) atomicAdd(&cnt[row[i]], 1);
}

// exclusive scan, 256/block: partial scan + per-block sums
__global__ __launch_bounds__(256) void scan1_kernel(
    const int* __restrict__ cnt, int* __restrict__ offs, int* __restrict__ bsums) {
    __shared__ int s[256];
    int tid = threadIdx.x;
    int i = blockIdx.x * 256 + tid;
    int v = (i < N_NODES) ? cnt[i] : 0;
    s[tid] = v;
    __syncthreads();
    #pragma unroll
    for (int d = 1; d < 256; d <<= 1) {
        int t = (tid >= d) ? s[tid - d] : 0;
        __syncthreads();
        s[tid] += t;
        __syncthreads();
    }
    if (i < N_NODES) offs[i] = s[tid] - v;   // exclusive
    if (tid == 255) bsums[blockIdx.x] = s[255];
}

// scan the 391 block sums in one 512-thread block
__global__ __launch_bounds__(512) void scan2_kernel(
    int* __restrict__ bsums, int* __restrict__ offs, int E, int nb) {
    __shared__ int s[512];
    int tid = threadIdx.x;
    int v = (tid < nb) ? bsums[tid] : 0;
    s[tid] = v;
    __syncthreads();
    #pragma unroll
    for (int d = 1; d < 512; d <<= 1) {
        int t = (tid >= d) ? s[tid - d] : 0;
        __syncthreads();
        s[tid] += t;
        __syncthreads();
    }
    if (tid < nb) bsums[tid] = s[tid] - v;   // exclusive block prefix
    if (tid == 0) offs[N_NODES] = E;
}

__global__ __launch_bounds__(256) void scan3_kernel(
    int* __restrict__ offs, int* __restrict__ cur, const int* __restrict__ bsums) {
    int i = blockIdx.x * 256 + threadIdx.x;
    if (i < N_NODES) {
        int o = offs[i] + bsums[blockIdx.x];
        offs[i] = o;
        cur[i] = o;
    }
}

// scatter edges into row-grouped order: (col, val) packed as int2 (one 8B store)
__global__ __launch_bounds__(256) void scatter_kernel(
    const int* __restrict__ row, const int* __restrict__ col,
    const float* __restrict__ val, int* __restrict__ cur,
    int2* __restrict__ cv, int E) {
    int i = blockIdx.x * 256 + threadIdx.x;
    int n = gridDim.x * 256;
    for (; i < E; i += n) {
        int r = row[i];
        int pos = atomicAdd(&cur[r], 1);
        cv[pos] = make_int2(col[i], __float_as_int(val[i]));
    }
}

// gather-only segment reduction: one wave per row, register accumulate, one write
__global__ __launch_bounds__(256) void csr_kernel(
    const int* __restrict__ offs, const int2* __restrict__ cv,
    const float* __restrict__ support, float* __restrict__ out) {
    int w = (blockIdx.x * 256 + threadIdx.x) >> 6;   // row
    int lane = threadIdx.x & 63;
    if (w >= N_NODES) return;
    int e = offs[w], e1 = offs[w + 1];
    float a0 = 0.f, a1 = 0.f;
    for (; e + 3 < e1; e += 4) {
        int2 c0 = cv[e], c1 = cv[e + 1], c2 = cv[e + 2], c3 = cv[e + 3];
        float2 x0 = *(const float2*)(support + (long long)c0.x * OUT_F + lane * 2);
        float2 x1 = *(const float2*)(support + (long long)c1.x * OUT_F + lane * 2);
        float2 x2 = *(const float2*)(support + (long long)c2.x * OUT_F + lane * 2);
        float2 x3 = *(const float2*)(support + (long long)c3.x * OUT_F + lane * 2);
        a0 = fmaf(__int_as_float(c0.y), x0.x, a0); a1 = fmaf(__int_as_float(c0.y), x0.y, a1);
        a0 = fmaf(__int_as_float(c1.y), x1.x, a0); a1 = fmaf(__int_as_float(c1.y), x1.y, a1);
        a0 = fmaf(__int_as_float(c2.y), x2.x, a0); a1 = fmaf(__int_as_float(c2.y), x2.y, a1);
        a0 = fmaf(__int_as_float(c3.y), x3.x, a0); a1 = fmaf(__int_as_float(c3.y), x3.y, a1);
    }
    for (; e < e1; ++e) {
        int2 c = cv[e];
        float2 x = *(const float2*)(support + (long long)c.x * OUT_F + lane * 2);
        a0 = fmaf(__int_as_float(c.y), x.x, a0);
        a1 = fmaf(__int_as_float(c.y), x.y, a1);
    }
    *(float2*)(out + (long long)w * OUT_F + lane * 2) = make_float2(a0, a1);
}

extern "C" void kernel_launch(void* const* d_in, const int* in_sizes, int n_in,
                              void* d_out, int out_size, void* d_ws, size_t ws_size,
                              hipStream_t stream) {
    const float* input   = (const float*)d_in[0];
    const float* weight  = (const float*)d_in[1];
    const int*   adj_row = (const int*)d_in[2];
    const int*   adj_col = (const int*)d_in[3];
    const float* adj_val = (const float*)d_in[4];
    const float* drop_u  = (const float*)d_in[5];
    float* out = (float*)d_out;
    const int E = in_sizes[2];

    // ws layout (bytes):
    //   [0, 64K)              bt       bf16 [128][256]
    //   [64K, +51.2M)         support  fp32 [N][128]
    //   then: offs (N+1 ints), cnt/cur (N ints), bsums (512 ints), cv (E int2)
    char* p = (char*)d_ws;
    unsigned short* bt = (unsigned short*)p;                 p += 65536;
    float* support     = (float*)p;                          p += (size_t)N_NODES * OUT_F * 4;
    int* offs          = (int*)p;                            p += ((size_t)N_NODES + 2) * 4;  // keep 8B align
    int* cnt_cur       = (int*)p;                            p += (size_t)N_NODES * 4;
    int* bsums         = (int*)p;                            p += 512 * 4;
    int2* cv           = (int2*)p;

    hipMemsetAsync(cnt_cur, 0, (size_t)N_NODES * sizeof(int), stream);
    wt_kernel<<<128, 256, 0, stream>>>(weight, bt);
    gemm_kernel<<<(N_NODES + 127) / 128, 256, 0, stream>>>(input, drop_u, bt, support);
    hist_kernel<<<2048, 256, 0, stream>>>(adj_row, cnt_cur, E);
    scan1_kernel<<<NB_SCAN, 256, 0, stream>>>(cnt_cur, offs, bsums);
    scan2_kernel<<<1, 512, 0, stream>>>(bsums, offs, E, NB_SCAN);
    scan3_kernel<<<NB_SCAN, 256, 0, stream>>>(offs, cnt_cur, bsums);
    scatter_kernel<<<2048, 256, 0, stream>>>(adj_row, adj_col, adj_val, cnt_cur, cv, E);
    csr_kernel<<<(N_NODES * 64 + 255) / 256, 256, 0, stream>>>(offs, cv, support, out);
}